// Round 11
// baseline (119.653 us; speedup 1.0000x reference)
//
#include <hip/hip_runtime.h>
#include <math.h>

// Problem constants
#define B_  8
#define D_  128
#define L_  2048
#define H_  8
#define DH_ 16

#define LOG2E 1.4426950408889634f

typedef __bf16 bf16x8 __attribute__((ext_vector_type(8)));
typedef float  floatx4 __attribute__((ext_vector_type(4)));
typedef float  floatx16 __attribute__((ext_vector_type(16)));

#if __has_builtin(__builtin_amdgcn_exp2f)
#define EXP2(x) __builtin_amdgcn_exp2f(x)
#else
#define EXP2(x) exp2f(x)
#endif

// tau: swap bits 2,3 of a row index (K A-frag row permutation, involution
// within each aligned 16-row group; bijection on [0,L)).
__device__ __forceinline__ int tau16(int x) {
  return (x & ~12) | ((x & 4) << 1) | ((x & 8) >> 1);
}

// ---------------------------------------------------------------------------
// prep = scan (blocks 0-7) + wconv (blocks 8-31), fused (round-9, unchanged).
// Measured-by-closure: ~2 us (v18 landed on its 97-100 prediction).
// ---------------------------------------------------------------------------
__global__ __launch_bounds__(256) void prep_kernel(
    const int* __restrict__ mask, int* __restrict__ pos,
    int* __restrict__ cnt, __bf16* __restrict__ Ksc,
    __bf16* __restrict__ Vpc, const float* __restrict__ wmem,
    const float* __restrict__ wq, __bf16* __restrict__ Wb) {
  const int blk = blockIdx.x;
  const int tid = threadIdx.x;

  if (blk >= 8) {  // ---- wconv: tile = blk - 8 ----
    const int tile = blk - 8;
    const int kc = tid >> 6, lane = tid & 63;
    const int quad = lane >> 4, col = lane & 15;
    const float* src;
    float scale = 1.0f;
    if (tile < 8) {
      src = wq + (tile * 16 + col) * D_;
      scale = 0.25f * LOG2E;  // DH^-0.5 and log2e folded into W_q
    } else if (tile < 16) {
      src = wmem + ((tile - 8) * 16 + col) * D_;
    } else {
      src = wmem + (128 + (tile - 16) * 16 + col) * D_;
    }
    const float* p = src + kc * 32 + quad * 8;
    bf16x8 w;
#pragma unroll
    for (int j = 0; j < 8; ++j) w[j] = (__bf16)(p[j] * scale);
    *(bf16x8*)(Wb + ((size_t)((tile * 4 + kc) * 64) + lane) * 8) = w;
    return;
  }

  // ---- scan: batch b = blk ----
  __shared__ int wsum[4];
  const int b = blk;
  const int lane = tid & 63, wv = tid >> 6;
  int m[8], s = 0;
  const int* mp = mask + b * L_ + tid * 8;
#pragma unroll
  for (int j = 0; j < 8; ++j) { m[j] = mp[j]; s += m[j]; }
  // 64-lane inclusive scan of per-thread sums.
  int x = s;
#pragma unroll
  for (int off = 1; off < 64; off <<= 1) {
    int v = __shfl_up(x, off, 64);
    if (lane >= off) x += v;
  }
  if (lane == 63) wsum[wv] = x;
  __syncthreads();
  int base = 0;
#pragma unroll
  for (int w = 0; w < 4; ++w) base += (w < wv) ? wsum[w] : 0;
  const int total = wsum[0] + wsum[1] + wsum[2] + wsum[3];
  if (tid == 0) cnt[b] = total;
  // exclusive prefix for this thread's 8 mask entries.
  int p = base + x - s;
  int* pb = pos + b * L_;
#pragma unroll
  for (int j = 0; j < 8; ++j) {
    if (m[j]) pb[tid * 8 + j] = p++;
  }
  // zero-pad [cnt, pend): thread -> (head, dp). Pad contributes exactly 0
  // (K=0 -> exp2(0)=1 x V=0; mask row 0).
  const int cn = total;
  const int pend = ((cn + 31) >> 5) << 5;
  const int hID = tid >> 5, dp = tid & 31;
  const int pp = cn + dp;
  if (pp < pend) {
    const size_t bh = (size_t)(b * H_ + hID);
    bf16x8 z = {};
    bf16x8* kd = (bf16x8*)(Ksc + (bh * L_ + tau16(pp)) * DH_);
    kd[0] = z;
    kd[1] = z;
    __bf16* vd = Vpc + (bh * 32) * (size_t)L_ + pp;
#pragma unroll
    for (int r = 0; r <= 16; ++r) vd[(size_t)r * L_] = (__bf16)0.0f;
  }
}

// ---------------------------------------------------------------------------
// Projection v4 (round-7 structure, byte-identical): compaction folded in.
// Directly measured (v17 4x-dispatch): 10.0 us.
// ---------------------------------------------------------------------------
__global__ __launch_bounds__(256) void proj_kernel(
    const float* __restrict__ qin, const int* __restrict__ mask,
    const int* __restrict__ pos, const __bf16* __restrict__ Wb,
    __bf16* __restrict__ Qs, __bf16* __restrict__ Ksc,
    __bf16* __restrict__ Vpc) {
  __shared__ float xl[16][132];        // row stride >= 128 (D)!
  __shared__ __bf16 Qst[8][16][16];    // [head][l-row][col]
  __shared__ __bf16 Kst[8][16][16];    // [head][natural l-row][dh-col]
  __shared__ __bf16 Vst[8][16][16];    // [head][dh-row][l-col]
  const int b = blockIdx.x >> 7;
  const int l0 = (blockIdx.x & 127) * 16;
  const int tid = threadIdx.x;

#pragma unroll
  for (int i = 0; i < 2; ++i) {
    int idx = i * 256 + tid;
    int d = idx >> 2;
    int l4 = (idx & 3) * 4;
    const float4 v = *(const float4*)&qin[(b * D_ + d) * L_ + l0 + l4];
    xl[l4 + 0][d] = v.x;
    xl[l4 + 1][d] = v.y;
    xl[l4 + 2][d] = v.z;
    xl[l4 + 3][d] = v.w;
  }
  __syncthreads();

  const int lane = tid & 63, wave = tid >> 6;
  const int quad = lane >> 4, col = lane & 15;

  bf16x8 af[4];
#pragma unroll
  for (int kc = 0; kc < 4; ++kc) {
    const float* s = &xl[col][kc * 32 + quad * 8];
#pragma unroll
    for (int j = 0; j < 8; ++j) af[kc][j] = (__bf16)s[j];
  }

#pragma unroll
  for (int tt = 0; tt < 6; ++tt) {
    const int tile = wave * 6 + tt;
    floatx4 acc = {0.f, 0.f, 0.f, 0.f};
    const bool isV = (tile >= 16);
#pragma unroll
    for (int kc = 0; kc < 4; ++kc) {
      bf16x8 wf =
          *(const bf16x8*)(Wb + ((size_t)((tile * 4 + kc) * 64) + lane) * 8);
      acc = isV ? __builtin_amdgcn_mfma_f32_16x16x32_bf16(wf, af[kc], acc, 0, 0, 0)
                : __builtin_amdgcn_mfma_f32_16x16x32_bf16(af[kc], wf, acc, 0, 0, 0);
    }
    if (tile < 8) {  // Q head -> LDS
#pragma unroll
      for (int r = 0; r < 4; ++r) Qst[tile][quad * 4 + r][col] = (__bf16)acc[r];
    } else if (tile < 16) {  // K head -> LDS, natural rows
#pragma unroll
      for (int r = 0; r < 4; ++r)
        Kst[tile - 8][quad * 4 + r][col] = (__bf16)acc[r];
    } else {  // V^T -> LDS
#pragma unroll
      for (int r = 0; r < 4; ++r)
        Vst[tile - 16][quad * 4 + r][col] = (__bf16)acc[r];
    }
  }
  __syncthreads();

  // Q: coalesced 16B stores (unchanged).  K: compacted scattered 16B stores.
  {
    const int hID = tid >> 5;           // 0..7
    const int u = tid & 31;             // 0..31
    const int row = u >> 1, ch = (u & 1) * 8;
    const size_t bhq = (size_t)(b * H_ + hID);
    bf16x8 qv = *(const bf16x8*)&Qst[hID][row][ch];
    *(bf16x8*)(Qs + (bhq * L_ + l0 + row) * DH_ + ch) = qv;
    const int lK = l0 + row;
    if (mask[b * L_ + lK]) {
      const int p = pos[b * L_ + lK];
      bf16x8 kv = *(const bf16x8*)&Kst[hID][row][ch];
      *(bf16x8*)(Ksc + (bhq * L_ + tau16(p)) * DH_ + ch) = kv;
    }
  }
  // V: compacted column stores. thread -> (head, l-col); consecutive masked
  // cols -> consecutive p -> coalesced per dh-row. Mask row 16 = 1.0.
  if (tid < 128) {
    const int hV = tid >> 4, c = tid & 15;
    const int lV = l0 + c;
    if (mask[b * L_ + lV]) {
      const int p = pos[b * L_ + lV];
      __bf16* dst = Vpc + ((size_t)(b * H_ + hV) * 32) * L_ + p;
#pragma unroll
      for (int r = 0; r < 16; ++r) dst[(size_t)r * L_] = Vst[hV][r][c];
      dst[(size_t)16 * L_] = (__bf16)1.0f;
    }
  }
}

// ---------------------------------------------------------------------------
// Attention v19 = single-q, register-slim, 6 waves/SIMD.
//   Post-mortem v18 ledger: attn 20.3us = ~9.2us issue (7us of it the
//   inherent one-exp-per-(q,key) trans floor) + ~11us stall at 4 waves/SIMD.
//   Dual-q's 2-acc/2-s/4-p live set (~115-130 VGPR) pins occupancy at 4.
//   v19: single q-group per wave (acc 16 + qf 4 + two named KV stages 24 +
//   transient s/p 24 + addr ~14 = ~82 <= 84 = 512/6 cap) -> honest
//   __launch_bounds__(256,6). Per-SIMD exp total unchanged; +50% waves to
//   fill MFMA-latency + trans-serialization stalls. Gives back dual-q's
//   load amortization (~6.5MB extra L1 reads; loop is 16 exp : 3 loads,
//   still trans-dominated).
// grid = B*H*(L/64) = 2048 blocks x 4 waves
//   wave = (pair, half): pair -> 32 q-rows, half -> ~16.5 kv-tiles.
// ---------------------------------------------------------------------------
__global__ __launch_bounds__(256, 6) void attn_kernel(
    const __bf16* __restrict__ Qs, const __bf16* __restrict__ Ks,
    const __bf16* __restrict__ Vp, const int* __restrict__ cnt,
    float* __restrict__ out) {
  __shared__ float red[2][64][17];  // 16 parked floats/lane, pad stride 17
  const int idx = blockIdx.x;
  const int qb = idx >> 6;        // 32 q-blocks of 64 rows
  const int bhi = idx & 63;       // bh minor -> idx%8 = h fixed per bh (XCD)
  const int h = bhi & 7;
  const int b = bhi >> 3;
  const int tid = threadIdx.x;
  const int lane = tid & 63, wave = tid >> 6;
  const int pair = wave >> 1;     // which 32 q-rows of this block
  const int half = wave & 1;      // which chunk of KV tiles
  const int n = lane & 31, hh = lane >> 5;
  const int q0 = qb * 64 + pair * 32;
  const size_t bh = (size_t)(b * H_ + h);

  // dynamic tile range: [tb, tb+ntw) of nt = ceil(cnt/32) compacted tiles
  const int cn = cnt[b];
  const int nt = (cn + 31) >> 5;
  const int nh0 = (nt + 1) >> 1;
  const int tb = half ? nh0 : 0;
  const int ntw = half ? (nt - nh0) : nh0;

  // Q B-frag: B[k=dh=8*hh+j][n=q] for q-row q0+n
  const bf16x8 qf = *(const bf16x8*)(Qs + (bh * L_ + q0 + n) * DH_ + 8 * hh);

  const __bf16* Kp = Ks + bh * L_ * DH_ + (size_t)n * DH_ + 8 * hh +
                     (size_t)tb * 32 * DH_;
  const __bf16* Vq = Vp + (bh * 32 + n) * (size_t)L_ + 8 * hh +
                     (size_t)tb * 32;

  floatx16 acc;
#pragma unroll
  for (int r = 0; r < 16; ++r) acc[r] = 0.f;
  const floatx16 zz = acc;

  // one KV tile; all operands are named registers (no dynamic indexing).
  auto compute = [&](const bf16x8& KF, const bf16x8& VA, const bf16x8& VB) {
    floatx16 s = __builtin_amdgcn_mfma_f32_32x32x16_bf16(KF, qf, zz, 0, 0, 0);
    bf16x8 pA, pB;
#pragma unroll
    for (int j = 0; j < 8; ++j) pA[j] = (__bf16)EXP2(s[j]);
#pragma unroll
    for (int j = 0; j < 8; ++j) pB[j] = (__bf16)EXP2(s[8 + j]);
    acc = __builtin_amdgcn_mfma_f32_32x32x16_bf16(VA, pA, acc, 0, 0, 0);
    acc = __builtin_amdgcn_mfma_f32_32x32x16_bf16(VB, pB, acc, 0, 0, 0);
  };

  // prologue: tile 0 of this wave's range into stage A
  bf16x8 kA = *(const bf16x8*)(Kp);
  bf16x8 vaA = *(const bf16x8*)(Vq);
  bf16x8 vbA = *(const bf16x8*)(Vq + 16);
  bf16x8 kB, vaB, vbB;

  int t = 0;
#pragma unroll 1
  for (; t + 2 <= ntw; t += 2) {
    // load tile t+1 into B (consumed after compute(A) -> latency hidden)
    kB  = *(const bf16x8*)(Kp + (size_t)(t + 1) * 32 * DH_);
    vaB = *(const bf16x8*)(Vq + (size_t)(t + 1) * 32);
    vbB = *(const bf16x8*)(Vq + (size_t)(t + 1) * 32 + 16);
    compute(kA, vaA, vbA);
    // load tile t+2 into A (guarded: redundant in-bounds reload at range end)
    const size_t t2 = (size_t)((t + 2 < ntw) ? t + 2 : t + 1);
    kA  = *(const bf16x8*)(Kp + t2 * 32 * DH_);
    vaA = *(const bf16x8*)(Vq + t2 * 32);
    vbA = *(const bf16x8*)(Vq + t2 * 32 + 16);
    compute(kB, vaB, vbB);
  }
  if (t < ntw) {  // odd tail: last tile already resident in A
    compute(kA, vaA, vbA);
  }

  // cross-wave K-reduction: half 0 parks its partial acc, half 1 sums.
  if (half == 0) {
#pragma unroll
    for (int r = 0; r < 16; ++r) red[pair][lane][r] = acc[r];
  }
  __syncthreads();
  if (half == 0) return;
#pragma unroll
  for (int r = 0; r < 16; ++r) acc[r] += red[pair][lane][r];

  // l = row 16 of O^T = acc reg 8 on the hh==0 half; broadcast to hh==1.
  float lmine = acc[8];
  float lother = __shfl_xor(lmine, 32, 64);
  float inv = __builtin_amdgcn_rcpf(hh ? lother : lmine);

  // regs 0-7 are the 8 valid dh rows for this half: dh = (r&3)+8*(r>>2)+4*hh
  float* obase = out + ((size_t)(b * D_ + h * DH_)) * L_ + q0 + n;
#pragma unroll
  for (int r = 0; r < 8; ++r) {
    const int dh = (r & 3) + 8 * (r >> 2) + 4 * hh;
    obase[(size_t)dh * L_] = acc[r] * inv;
  }
}

// ---------------------------------------------------------------------------
extern "C" void kernel_launch(void* const* d_in, const int* in_sizes, int n_in,
                              void* d_out, int out_size, void* d_ws,
                              size_t ws_size, hipStream_t stream) {
  const float* queries = (const float*)d_in[0];  // [B, D, L] fp32
  const int*   mask    = (const int*)d_in[1];    // [B, L] int32
  const float* wmem    = (const float*)d_in[2];  // [2D, D] fp32
  const float* wq      = (const float*)d_in[3];  // [D, D] fp32
  float* out = (float*)d_out;                    // [B, D, L] fp32

  // Workspace layout (SEG = 4 MiB):
  //   0: Qs | 1: Ksc (compacted, tau rows) | 2-3: Vpc flat [bh][32][L] |
  //   4: pos [B][L] int (64KB) + cnt [B] int
  const size_t SEG = (size_t)B_ * H_ * L_ * DH_ * sizeof(__bf16);
  __bf16* Qs  = (__bf16*)d_ws;
  __bf16* Ksc = (__bf16*)((char*)d_ws + SEG);
  __bf16* Vpc = (__bf16*)((char*)d_ws + 2 * SEG);
  int* pos = (int*)((char*)d_ws + 4 * SEG);
  int* cnt = pos + B_ * L_;

  // Wb (96 KiB) in d_out scratch: prep writes, proj reads, attn then
  // overwrites ALL of d_out — stream-ordered, race-free.
  __bf16* Wb = (__bf16*)((char*)d_out + (4u << 20));

  prep_kernel<<<32, 256, 0, stream>>>(mask, pos, cnt, Ksc, Vpc, wmem, wq, Wb);
  proj_kernel<<<B_ * (L_ / 16), 256, 0, stream>>>(queries, mask, pos, Wb, Qs,
                                                  Ksc, Vpc);
  attn_kernel<<<B_ * H_ * (L_ / 64), 256, 0, stream>>>(Qs, Ksc, Vpc, cnt, out);
}

// Round 12
// 100.761 us; speedup vs baseline: 1.1875x; 1.1875x over previous
//
#include <hip/hip_runtime.h>
#include <math.h>

// Problem constants
#define B_  8
#define D_  128
#define L_  2048
#define H_  8
#define DH_ 16

#define LOG2E 1.4426950408889634f

typedef __bf16 bf16x8 __attribute__((ext_vector_type(8)));
typedef float  floatx4 __attribute__((ext_vector_type(4)));
typedef float  floatx16 __attribute__((ext_vector_type(16)));

#if __has_builtin(__builtin_amdgcn_exp2f)
#define EXP2(x) __builtin_amdgcn_exp2f(x)
#else
#define EXP2(x) exp2f(x)
#endif

// tau: swap bits 2,3 of a row index (K A-frag row permutation, involution
// within each aligned 16-row group; bijection on [0,L)).
__device__ __forceinline__ int tau16(int x) {
  return (x & ~12) | ((x & 4) << 1) | ((x & 8) >> 1);
}

// ---------------------------------------------------------------------------
// prep = scan (blocks 0-7) + wconv (blocks 8-31), fused (round-9, unchanged).
// ---------------------------------------------------------------------------
__global__ __launch_bounds__(256) void prep_kernel(
    const int* __restrict__ mask, int* __restrict__ pos,
    int* __restrict__ cnt, __bf16* __restrict__ Ksc,
    __bf16* __restrict__ Vpc, const float* __restrict__ wmem,
    const float* __restrict__ wq, __bf16* __restrict__ Wb) {
  const int blk = blockIdx.x;
  const int tid = threadIdx.x;

  if (blk >= 8) {  // ---- wconv: tile = blk - 8 ----
    const int tile = blk - 8;
    const int kc = tid >> 6, lane = tid & 63;
    const int quad = lane >> 4, col = lane & 15;
    const float* src;
    float scale = 1.0f;
    if (tile < 8) {
      src = wq + (tile * 16 + col) * D_;
      scale = 0.25f * LOG2E;  // DH^-0.5 and log2e folded into W_q
    } else if (tile < 16) {
      src = wmem + ((tile - 8) * 16 + col) * D_;
    } else {
      src = wmem + (128 + (tile - 16) * 16 + col) * D_;
    }
    const float* p = src + kc * 32 + quad * 8;
    bf16x8 w;
#pragma unroll
    for (int j = 0; j < 8; ++j) w[j] = (__bf16)(p[j] * scale);
    *(bf16x8*)(Wb + ((size_t)((tile * 4 + kc) * 64) + lane) * 8) = w;
    return;
  }

  // ---- scan: batch b = blk ----
  __shared__ int wsum[4];
  const int b = blk;
  const int lane = tid & 63, wv = tid >> 6;
  int m[8], s = 0;
  const int* mp = mask + b * L_ + tid * 8;
#pragma unroll
  for (int j = 0; j < 8; ++j) { m[j] = mp[j]; s += m[j]; }
  // 64-lane inclusive scan of per-thread sums.
  int x = s;
#pragma unroll
  for (int off = 1; off < 64; off <<= 1) {
    int v = __shfl_up(x, off, 64);
    if (lane >= off) x += v;
  }
  if (lane == 63) wsum[wv] = x;
  __syncthreads();
  int base = 0;
#pragma unroll
  for (int w = 0; w < 4; ++w) base += (w < wv) ? wsum[w] : 0;
  const int total = wsum[0] + wsum[1] + wsum[2] + wsum[3];
  if (tid == 0) cnt[b] = total;
  // exclusive prefix for this thread's 8 mask entries.
  int p = base + x - s;
  int* pb = pos + b * L_;
#pragma unroll
  for (int j = 0; j < 8; ++j) {
    if (m[j]) pb[tid * 8 + j] = p++;
  }
  // zero-pad [cnt, pend): thread -> (head, dp). Pad contributes exactly 0
  // (K=0 -> exp2(0)=1 x V=0; mask row 0).
  const int cn = total;
  const int pend = ((cn + 31) >> 5) << 5;
  const int hID = tid >> 5, dp = tid & 31;
  const int pp = cn + dp;
  if (pp < pend) {
    const size_t bh = (size_t)(b * H_ + hID);
    bf16x8 z = {};
    bf16x8* kd = (bf16x8*)(Ksc + (bh * L_ + tau16(pp)) * DH_);
    kd[0] = z;
    kd[1] = z;
    __bf16* vd = Vpc + (bh * 32) * (size_t)L_ + pp;
#pragma unroll
    for (int r = 0; r <= 16; ++r) vd[(size_t)r * L_] = (__bf16)0.0f;
  }
}

// ---------------------------------------------------------------------------
// Projection v4 (round-7 structure, byte-identical): compaction folded in.
// Directly measured (v17 4x-dispatch): 10.0 us.
// ---------------------------------------------------------------------------
__global__ __launch_bounds__(256) void proj_kernel(
    const float* __restrict__ qin, const int* __restrict__ mask,
    const int* __restrict__ pos, const __bf16* __restrict__ Wb,
    __bf16* __restrict__ Qs, __bf16* __restrict__ Ksc,
    __bf16* __restrict__ Vpc) {
  __shared__ float xl[16][132];        // row stride >= 128 (D)!
  __shared__ __bf16 Qst[8][16][16];    // [head][l-row][col]
  __shared__ __bf16 Kst[8][16][16];    // [head][natural l-row][dh-col]
  __shared__ __bf16 Vst[8][16][16];    // [head][dh-row][l-col]
  const int b = blockIdx.x >> 7;
  const int l0 = (blockIdx.x & 127) * 16;
  const int tid = threadIdx.x;

#pragma unroll
  for (int i = 0; i < 2; ++i) {
    int idx = i * 256 + tid;
    int d = idx >> 2;
    int l4 = (idx & 3) * 4;
    const float4 v = *(const float4*)&qin[(b * D_ + d) * L_ + l0 + l4];
    xl[l4 + 0][d] = v.x;
    xl[l4 + 1][d] = v.y;
    xl[l4 + 2][d] = v.z;
    xl[l4 + 3][d] = v.w;
  }
  __syncthreads();

  const int lane = tid & 63, wave = tid >> 6;
  const int quad = lane >> 4, col = lane & 15;

  bf16x8 af[4];
#pragma unroll
  for (int kc = 0; kc < 4; ++kc) {
    const float* s = &xl[col][kc * 32 + quad * 8];
#pragma unroll
    for (int j = 0; j < 8; ++j) af[kc][j] = (__bf16)s[j];
  }

#pragma unroll
  for (int tt = 0; tt < 6; ++tt) {
    const int tile = wave * 6 + tt;
    floatx4 acc = {0.f, 0.f, 0.f, 0.f};
    const bool isV = (tile >= 16);
#pragma unroll
    for (int kc = 0; kc < 4; ++kc) {
      bf16x8 wf =
          *(const bf16x8*)(Wb + ((size_t)((tile * 4 + kc) * 64) + lane) * 8);
      acc = isV ? __builtin_amdgcn_mfma_f32_16x16x32_bf16(wf, af[kc], acc, 0, 0, 0)
                : __builtin_amdgcn_mfma_f32_16x16x32_bf16(af[kc], wf, acc, 0, 0, 0);
    }
    if (tile < 8) {  // Q head -> LDS
#pragma unroll
      for (int r = 0; r < 4; ++r) Qst[tile][quad * 4 + r][col] = (__bf16)acc[r];
    } else if (tile < 16) {  // K head -> LDS, natural rows
#pragma unroll
      for (int r = 0; r < 4; ++r)
        Kst[tile - 8][quad * 4 + r][col] = (__bf16)acc[r];
    } else {  // V^T -> LDS
#pragma unroll
      for (int r = 0; r < 4; ++r)
        Vst[tile - 16][quad * 4 + r][col] = (__bf16)acc[r];
    }
  }
  __syncthreads();

  // Q: coalesced 16B stores (unchanged).  K: compacted scattered 16B stores.
  {
    const int hID = tid >> 5;           // 0..7
    const int u = tid & 31;             // 0..31
    const int row = u >> 1, ch = (u & 1) * 8;
    const size_t bhq = (size_t)(b * H_ + hID);
    bf16x8 qv = *(const bf16x8*)&Qst[hID][row][ch];
    *(bf16x8*)(Qs + (bhq * L_ + l0 + row) * DH_ + ch) = qv;
    const int lK = l0 + row;
    if (mask[b * L_ + lK]) {
      const int p = pos[b * L_ + lK];
      bf16x8 kv = *(const bf16x8*)&Kst[hID][row][ch];
      *(bf16x8*)(Ksc + (bhq * L_ + tau16(p)) * DH_ + ch) = kv;
    }
  }
  // V: compacted column stores. thread -> (head, l-col); consecutive masked
  // cols -> consecutive p -> coalesced per dh-row. Mask row 16 = 1.0.
  if (tid < 128) {
    const int hV = tid >> 4, c = tid & 15;
    const int lV = l0 + c;
    if (mask[b * L_ + lV]) {
      const int p = pos[b * L_ + lV];
      __bf16* dst = Vpc + ((size_t)(b * H_ + hV) * 32) * L_ + p;
#pragma unroll
      for (int r = 0; r < 16; ++r) dst[(size_t)r * L_] = Vst[hV][r][c];
      dst[(size_t)16 * L_] = (__bf16)1.0f;
    }
  }
}

// ---------------------------------------------------------------------------
// Attention v20 = REVERT to the verified round-6/round-10 dual-q structure.
//   Post-mortem v19: single-q "6 waves/SIMD" allocated 160 VGPR anyway
//   (launch_bounds min-waves request not honored below the scheduler's
//   live-range floor; same failure as v9) -> 3 waves/SIMD AND half the
//   exp:load ratio -> attn 20.3 -> 47.5us. Dual-q 4-wave is the verified
//   optimum of every {ILP x occupancy x traffic} corner tried
//   (v8/v9/v10/v11/v19 all >= its time). Directly measured: 20.3 us.
// grid = B*H*(L/128) = 1024 blocks x 4 waves (wave: 64 q x ~16 kv-tiles).
// ---------------------------------------------------------------------------
__global__ __launch_bounds__(256, 4) void attn_kernel(
    const __bf16* __restrict__ Qs, const __bf16* __restrict__ Ks,
    const __bf16* __restrict__ Vp, const int* __restrict__ cnt,
    float* __restrict__ out) {
  __shared__ float red[2][64][33];  // 32 parked floats/lane, pad stride 33
  const int idx = blockIdx.x;
  const int qb = idx >> 6;        // 16 q-blocks of 128 rows
  const int bhi = idx & 63;       // bh minor -> idx%8 = h fixed per bh (XCD)
  const int h = bhi & 7;
  const int b = bhi >> 3;
  const int tid = threadIdx.x;
  const int lane = tid & 63, wave = tid >> 6;
  const int pair = wave >> 1;     // which 64 q-rows of this block
  const int half = wave & 1;      // which chunk of KV tiles
  const int n = lane & 31, hh = lane >> 5;
  const int q0 = qb * 128 + pair * 64;
  const size_t bh = (size_t)(b * H_ + h);

  // dynamic tile range: [tb, tb+ntw) of nt = ceil(cnt/32) compacted tiles
  const int cn = cnt[b];
  const int nt = (cn + 31) >> 5;
  const int nh0 = (nt + 1) >> 1;
  const int tb = half ? nh0 : 0;
  const int ntw = half ? (nt - nh0) : nh0;

  // Q B-frags: B[k=dh=8*hh+j][n=q] for q-rows q0+n and q0+32+n
  const bf16x8 qf0 = *(const bf16x8*)(Qs + (bh * L_ + q0 + n) * DH_ + 8 * hh);
  const bf16x8 qf1 =
      *(const bf16x8*)(Qs + (bh * L_ + q0 + 32 + n) * DH_ + 8 * hh);

  const __bf16* Kp = Ks + bh * L_ * DH_ + (size_t)n * DH_ + 8 * hh +
                     (size_t)tb * 32 * DH_;
  const __bf16* Vq = Vp + (bh * 32 + n) * (size_t)L_ + 8 * hh +
                     (size_t)tb * 32;

  floatx16 acc0, acc1;
#pragma unroll
  for (int r = 0; r < 16; ++r) { acc0[r] = 0.f; acc1[r] = 0.f; }
  const floatx16 zz = acc0;

  // one KV tile against both q-groups; all operands are named registers.
  auto compute = [&](const bf16x8& KF, const bf16x8& VA, const bf16x8& VB) {
    floatx16 s0 = __builtin_amdgcn_mfma_f32_32x32x16_bf16(KF, qf0, zz, 0, 0, 0);
    floatx16 s1 = __builtin_amdgcn_mfma_f32_32x32x16_bf16(KF, qf1, zz, 0, 0, 0);
    bf16x8 pA0, pB0, pA1, pB1;
#pragma unroll
    for (int j = 0; j < 8; ++j) pA0[j] = (__bf16)EXP2(s0[j]);
#pragma unroll
    for (int j = 0; j < 8; ++j) pB0[j] = (__bf16)EXP2(s0[8 + j]);
#pragma unroll
    for (int j = 0; j < 8; ++j) pA1[j] = (__bf16)EXP2(s1[j]);
#pragma unroll
    for (int j = 0; j < 8; ++j) pB1[j] = (__bf16)EXP2(s1[8 + j]);
    acc0 = __builtin_amdgcn_mfma_f32_32x32x16_bf16(VA, pA0, acc0, 0, 0, 0);
    acc0 = __builtin_amdgcn_mfma_f32_32x32x16_bf16(VB, pB0, acc0, 0, 0, 0);
    acc1 = __builtin_amdgcn_mfma_f32_32x32x16_bf16(VA, pA1, acc1, 0, 0, 0);
    acc1 = __builtin_amdgcn_mfma_f32_32x32x16_bf16(VB, pB1, acc1, 0, 0, 0);
  };

  // prologue: tile 0 of this wave's range into stage A
  bf16x8 kA = *(const bf16x8*)(Kp);
  bf16x8 vaA = *(const bf16x8*)(Vq);
  bf16x8 vbA = *(const bf16x8*)(Vq + 16);
  bf16x8 kB, vaB, vbB;

  int t = 0;
#pragma unroll 1
  for (; t + 2 <= ntw; t += 2) {
    // load tile t+1 into B (consumed after compute(A) -> latency hidden)
    kB  = *(const bf16x8*)(Kp + (size_t)(t + 1) * 32 * DH_);
    vaB = *(const bf16x8*)(Vq + (size_t)(t + 1) * 32);
    vbB = *(const bf16x8*)(Vq + (size_t)(t + 1) * 32 + 16);
    compute(kA, vaA, vbA);
    // load tile t+2 into A (guarded: redundant in-bounds reload at range end)
    const size_t t2 = (size_t)((t + 2 < ntw) ? t + 2 : t + 1);
    kA  = *(const bf16x8*)(Kp + t2 * 32 * DH_);
    vaA = *(const bf16x8*)(Vq + t2 * 32);
    vbA = *(const bf16x8*)(Vq + t2 * 32 + 16);
    compute(kB, vaB, vbB);
  }
  if (t < ntw) {  // odd tail: last tile already resident in A
    compute(kA, vaA, vbA);
  }

  // cross-wave K-reduction: half 0 parks both partial accs, half 1 sums.
  if (half == 0) {
#pragma unroll
    for (int r = 0; r < 16; ++r) {
      red[pair][lane][r] = acc0[r];
      red[pair][lane][16 + r] = acc1[r];
    }
  }
  __syncthreads();
  if (half == 0) return;
#pragma unroll
  for (int r = 0; r < 16; ++r) {
    acc0[r] += red[pair][lane][r];
    acc1[r] += red[pair][lane][16 + r];
  }

  // l = row 16 of O^T = acc reg 8 on the hh==0 half; broadcast to hh==1.
  float l0v = acc0[8];
  float l0o = __shfl_xor(l0v, 32, 64);
  float inv0 = __builtin_amdgcn_rcpf(hh ? l0o : l0v);
  float l1v = acc1[8];
  float l1o = __shfl_xor(l1v, 32, 64);
  float inv1 = __builtin_amdgcn_rcpf(hh ? l1o : l1v);

  // regs 0-7 are the 8 valid dh rows for this half: dh = (r&3)+8*(r>>2)+4*hh
  float* obase = out + ((size_t)(b * D_ + h * DH_)) * L_ + q0 + n;
#pragma unroll
  for (int r = 0; r < 8; ++r) {
    const int dh = (r & 3) + 8 * (r >> 2) + 4 * hh;
    obase[(size_t)dh * L_] = acc0[r] * inv0;
    obase[(size_t)dh * L_ + 32] = acc1[r] * inv1;
  }
}

// ---------------------------------------------------------------------------
extern "C" void kernel_launch(void* const* d_in, const int* in_sizes, int n_in,
                              void* d_out, int out_size, void* d_ws,
                              size_t ws_size, hipStream_t stream) {
  const float* queries = (const float*)d_in[0];  // [B, D, L] fp32
  const int*   mask    = (const int*)d_in[1];    // [B, L] int32
  const float* wmem    = (const float*)d_in[2];  // [2D, D] fp32
  const float* wq      = (const float*)d_in[3];  // [D, D] fp32
  float* out = (float*)d_out;                    // [B, D, L] fp32

  // Workspace layout (SEG = 4 MiB):
  //   0: Qs | 1: Ksc (compacted, tau rows) | 2-3: Vpc flat [bh][32][L] |
  //   4: pos [B][L] int (64KB) + cnt [B] int
  const size_t SEG = (size_t)B_ * H_ * L_ * DH_ * sizeof(__bf16);
  __bf16* Qs  = (__bf16*)d_ws;
  __bf16* Ksc = (__bf16*)((char*)d_ws + SEG);
  __bf16* Vpc = (__bf16*)((char*)d_ws + 2 * SEG);
  int* pos = (int*)((char*)d_ws + 4 * SEG);
  int* cnt = pos + B_ * L_;

  // Wb (96 KiB) in d_out scratch: prep writes, proj reads, attn then
  // overwrites ALL of d_out — stream-ordered, race-free.
  __bf16* Wb = (__bf16*)((char*)d_out + (4u << 20));

  prep_kernel<<<32, 256, 0, stream>>>(mask, pos, cnt, Ksc, Vpc, wmem, wq, Wb);
  proj_kernel<<<B_ * (L_ / 16), 256, 0, stream>>>(queries, mask, pos, Wb, Qs,
                                                  Ksc, Vpc);
  attn_kernel<<<B_ * H_ * (L_ / 128), 256, 0, stream>>>(Qs, Ksc, Vpc, cnt, out);
}

// Round 13
// 95.222 us; speedup vs baseline: 1.2566x; 1.0582x over previous
//
#include <hip/hip_runtime.h>
#include <math.h>

// Problem constants
#define B_  8
#define D_  128
#define L_  2048
#define H_  8
#define DH_ 16

#define LOG2E 1.4426950408889634f

typedef __bf16 bf16x8 __attribute__((ext_vector_type(8)));
typedef float  floatx4 __attribute__((ext_vector_type(4)));
typedef float  floatx16 __attribute__((ext_vector_type(16)));

#if __has_builtin(__builtin_amdgcn_exp2f)
#define EXP2(x) __builtin_amdgcn_exp2f(x)
#else
#define EXP2(x) exp2f(x)
#endif

// tau: swap bits 2,3 of a row index (K A-frag row permutation, involution
// within each aligned 16-row group; bijection on [0,L)).
__device__ __forceinline__ int tau16(int x) {
  return (x & ~12) | ((x & 4) << 1) | ((x & 8) >> 1);
}

// ---------------------------------------------------------------------------
// prep = scan (blocks 0-7) + wconv (blocks 8-31), fused (round-9, unchanged).
// ---------------------------------------------------------------------------
__global__ __launch_bounds__(256) void prep_kernel(
    const int* __restrict__ mask, int* __restrict__ pos,
    int* __restrict__ cnt, __bf16* __restrict__ Ksc,
    __bf16* __restrict__ Vpc, const float* __restrict__ wmem,
    const float* __restrict__ wq, __bf16* __restrict__ Wb) {
  const int blk = blockIdx.x;
  const int tid = threadIdx.x;

  if (blk >= 8) {  // ---- wconv: tile = blk - 8 ----
    const int tile = blk - 8;
    const int kc = tid >> 6, lane = tid & 63;
    const int quad = lane >> 4, col = lane & 15;
    const float* src;
    float scale = 1.0f;
    if (tile < 8) {
      src = wq + (tile * 16 + col) * D_;
      scale = 0.25f * LOG2E;  // DH^-0.5 and log2e folded into W_q
    } else if (tile < 16) {
      src = wmem + ((tile - 8) * 16 + col) * D_;
    } else {
      src = wmem + (128 + (tile - 16) * 16 + col) * D_;
    }
    const float* p = src + kc * 32 + quad * 8;
    bf16x8 w;
#pragma unroll
    for (int j = 0; j < 8; ++j) w[j] = (__bf16)(p[j] * scale);
    *(bf16x8*)(Wb + ((size_t)((tile * 4 + kc) * 64) + lane) * 8) = w;
    return;
  }

  // ---- scan: batch b = blk ----
  __shared__ int wsum[4];
  const int b = blk;
  const int lane = tid & 63, wv = tid >> 6;
  int m[8], s = 0;
  const int* mp = mask + b * L_ + tid * 8;
#pragma unroll
  for (int j = 0; j < 8; ++j) { m[j] = mp[j]; s += m[j]; }
  // 64-lane inclusive scan of per-thread sums.
  int x = s;
#pragma unroll
  for (int off = 1; off < 64; off <<= 1) {
    int v = __shfl_up(x, off, 64);
    if (lane >= off) x += v;
  }
  if (lane == 63) wsum[wv] = x;
  __syncthreads();
  int base = 0;
#pragma unroll
  for (int w = 0; w < 4; ++w) base += (w < wv) ? wsum[w] : 0;
  const int total = wsum[0] + wsum[1] + wsum[2] + wsum[3];
  if (tid == 0) cnt[b] = total;
  // exclusive prefix for this thread's 8 mask entries.
  int p = base + x - s;
  int* pb = pos + b * L_;
#pragma unroll
  for (int j = 0; j < 8; ++j) {
    if (m[j]) pb[tid * 8 + j] = p++;
  }
  // zero-pad [cnt, pend): thread -> (head, dp). Pad contributes exactly 0
  // (K=0 -> exp2(0)=1 x V=0; mask row 0).
  const int cn = total;
  const int pend = ((cn + 31) >> 5) << 5;
  const int hID = tid >> 5, dp = tid & 31;
  const int pp = cn + dp;
  if (pp < pend) {
    const size_t bh = (size_t)(b * H_ + hID);
    bf16x8 z = {};
    bf16x8* kd = (bf16x8*)(Ksc + (bh * L_ + tau16(pp)) * DH_);
    kd[0] = z;
    kd[1] = z;
    __bf16* vd = Vpc + (bh * 32) * (size_t)L_ + pp;
#pragma unroll
    for (int r = 0; r <= 16; ++r) vd[(size_t)r * L_] = (__bf16)0.0f;
  }
}

// ---------------------------------------------------------------------------
// Projection v5: 32 l-rows/block, 512 threads (8 waves), dual x-fragment.
//   Post-mortem v20 ledger: proj = 10.0us vs ~3us data floor; excess is
//   latency on the Wb re-read (1024 blocks x 96KiB = 96MiB L2 traffic;
//   24 dependent 16B L2 loads/thread, each feeding ONE MFMA).
//   v5: each wf load feeds TWO MFMAs (x-frags A = l-rows 0-15 and
//   B = 16-31) -> Wb traffic halves (48MiB), per-load stall exposure
//   halves. 512 blocks x 8 waves = same total waves (4/SIMD); LDS 41.5KB
//   (2 blocks/CU by grid). Epilogue re-indexed for 32 rows: Q/K one 16B
//   unit/thread (single pass), V one (head,col)/thread for tid<256.
//   Compaction fold-in semantics unchanged (exact).
// grid = B * (L/32) = 512 blocks x 512 threads.
// ---------------------------------------------------------------------------
__global__ __launch_bounds__(512) void proj_kernel(
    const float* __restrict__ qin, const int* __restrict__ mask,
    const int* __restrict__ pos, const __bf16* __restrict__ Wb,
    __bf16* __restrict__ Qs, __bf16* __restrict__ Ksc,
    __bf16* __restrict__ Vpc) {
  __shared__ float xl[32][132];        // row stride >= 128 (D)!
  __shared__ __bf16 Qst[8][32][16];    // [head][l-row][dh-col]
  __shared__ __bf16 Kst[8][32][16];    // [head][natural l-row][dh-col]
  __shared__ __bf16 Vst[8][16][32];    // [head][dh-row][l-col]
  const int b = blockIdx.x >> 6;
  const int l0 = (blockIdx.x & 63) * 32;
  const int tid = threadIdx.x;

  // Stage x: 32 l x 128 d fp32 = 1024 float4, 512 threads, 2 iters.
#pragma unroll
  for (int i = 0; i < 2; ++i) {
    int idx = i * 512 + tid;
    int d = idx >> 3;
    int l4 = (idx & 7) * 4;
    const float4 v = *(const float4*)&qin[(b * D_ + d) * L_ + l0 + l4];
    xl[l4 + 0][d] = v.x;
    xl[l4 + 1][d] = v.y;
    xl[l4 + 2][d] = v.z;
    xl[l4 + 3][d] = v.w;
  }
  __syncthreads();

  const int lane = tid & 63, wave = tid >> 6;   // 8 waves
  const int quad = lane >> 4, col = lane & 15;

  // Two x-fragments: rows l0+col (A) and l0+16+col (B).
  bf16x8 afA[4], afB[4];
#pragma unroll
  for (int kc = 0; kc < 4; ++kc) {
    const float* sA = &xl[col][kc * 32 + quad * 8];
    const float* sB = &xl[16 + col][kc * 32 + quad * 8];
#pragma unroll
    for (int j = 0; j < 8; ++j) {
      afA[kc][j] = (__bf16)sA[j];
      afB[kc][j] = (__bf16)sB[j];
    }
  }

  // 24 tiles over 8 waves = 3 tiles/wave; each wf load feeds 2 MFMAs.
#pragma unroll
  for (int tt = 0; tt < 3; ++tt) {
    const int tile = wave * 3 + tt;
    floatx4 aA = {0.f, 0.f, 0.f, 0.f};
    floatx4 aB = {0.f, 0.f, 0.f, 0.f};
    const bool isV = (tile >= 16);
#pragma unroll
    for (int kc = 0; kc < 4; ++kc) {
      bf16x8 wf =
          *(const bf16x8*)(Wb + ((size_t)((tile * 4 + kc) * 64) + lane) * 8);
      if (isV) {
        aA = __builtin_amdgcn_mfma_f32_16x16x32_bf16(wf, afA[kc], aA, 0, 0, 0);
        aB = __builtin_amdgcn_mfma_f32_16x16x32_bf16(wf, afB[kc], aB, 0, 0, 0);
      } else {
        aA = __builtin_amdgcn_mfma_f32_16x16x32_bf16(afA[kc], wf, aA, 0, 0, 0);
        aB = __builtin_amdgcn_mfma_f32_16x16x32_bf16(afB[kc], wf, aB, 0, 0, 0);
      }
    }
    if (tile < 8) {  // Q head -> LDS (rows = l)
#pragma unroll
      for (int r = 0; r < 4; ++r) {
        Qst[tile][quad * 4 + r][col] = (__bf16)aA[r];
        Qst[tile][16 + quad * 4 + r][col] = (__bf16)aB[r];
      }
    } else if (tile < 16) {  // K head -> LDS, natural rows
#pragma unroll
      for (int r = 0; r < 4; ++r) {
        Kst[tile - 8][quad * 4 + r][col] = (__bf16)aA[r];
        Kst[tile - 8][16 + quad * 4 + r][col] = (__bf16)aB[r];
      }
    } else {  // V^T -> LDS (rows = dh, cols = l)
#pragma unroll
      for (int r = 0; r < 4; ++r) {
        Vst[tile - 16][quad * 4 + r][col] = (__bf16)aA[r];
        Vst[tile - 16][quad * 4 + r][16 + col] = (__bf16)aB[r];
      }
    }
  }
  __syncthreads();

  // Q + K: 8 heads x 64 16B-units; 512 threads -> exactly one unit each.
  {
    const int hID = tid >> 6;           // 0..7
    const int uu = tid & 63;            // 0..63
    const int row = uu >> 1, ch = (uu & 1) * 8;
    const size_t bhq = (size_t)(b * H_ + hID);
    bf16x8 qv = *(const bf16x8*)&Qst[hID][row][ch];
    *(bf16x8*)(Qs + (bhq * L_ + l0 + row) * DH_ + ch) = qv;
    const int lK = l0 + row;
    if (mask[b * L_ + lK]) {
      const int p = pos[b * L_ + lK];
      bf16x8 kv = *(const bf16x8*)&Kst[hID][row][ch];
      *(bf16x8*)(Ksc + (bhq * L_ + tau16(p)) * DH_ + ch) = kv;
    }
  }
  // V: 8 heads x 32 l-cols = 256 units -> tid < 256. Consecutive masked
  // cols -> consecutive p -> coalesced per dh-row. Mask row 16 = 1.0.
  if (tid < 256) {
    const int hV = tid >> 5, c = tid & 31;
    const int lV = l0 + c;
    if (mask[b * L_ + lV]) {
      const int p = pos[b * L_ + lV];
      __bf16* dst = Vpc + ((size_t)(b * H_ + hV) * 32) * L_ + p;
#pragma unroll
      for (int r = 0; r < 16; ++r) dst[(size_t)r * L_] = Vst[hV][r][c];
      dst[(size_t)16 * L_] = (__bf16)1.0f;
    }
  }
}

// ---------------------------------------------------------------------------
// Attention (verified dual-q structure, byte-identical): compacted keys,
// static 2-stage pipeline, K-split wave pairs, XCD remap, flat V.
// Directly measured (v15 4x-dispatch): 20.3 us. Six structural variants
// (v8/v9/v10/v11/v19) all >= this; do not touch without new evidence.
// grid = B*H*(L/128) = 1024 blocks x 4 waves (wave: 64 q x ~16 kv-tiles).
// ---------------------------------------------------------------------------
__global__ __launch_bounds__(256, 4) void attn_kernel(
    const __bf16* __restrict__ Qs, const __bf16* __restrict__ Ks,
    const __bf16* __restrict__ Vp, const int* __restrict__ cnt,
    float* __restrict__ out) {
  __shared__ float red[2][64][33];  // 32 parked floats/lane, pad stride 33
  const int idx = blockIdx.x;
  const int qb = idx >> 6;        // 16 q-blocks of 128 rows
  const int bhi = idx & 63;       // bh minor -> idx%8 = h fixed per bh (XCD)
  const int h = bhi & 7;
  const int b = bhi >> 3;
  const int tid = threadIdx.x;
  const int lane = tid & 63, wave = tid >> 6;
  const int pair = wave >> 1;     // which 64 q-rows of this block
  const int half = wave & 1;      // which chunk of KV tiles
  const int n = lane & 31, hh = lane >> 5;
  const int q0 = qb * 128 + pair * 64;
  const size_t bh = (size_t)(b * H_ + h);

  // dynamic tile range: [tb, tb+ntw) of nt = ceil(cnt/32) compacted tiles
  const int cn = cnt[b];
  const int nt = (cn + 31) >> 5;
  const int nh0 = (nt + 1) >> 1;
  const int tb = half ? nh0 : 0;
  const int ntw = half ? (nt - nh0) : nh0;

  // Q B-frags: B[k=dh=8*hh+j][n=q] for q-rows q0+n and q0+32+n
  const bf16x8 qf0 = *(const bf16x8*)(Qs + (bh * L_ + q0 + n) * DH_ + 8 * hh);
  const bf16x8 qf1 =
      *(const bf16x8*)(Qs + (bh * L_ + q0 + 32 + n) * DH_ + 8 * hh);

  const __bf16* Kp = Ks + bh * L_ * DH_ + (size_t)n * DH_ + 8 * hh +
                     (size_t)tb * 32 * DH_;
  const __bf16* Vq = Vp + (bh * 32 + n) * (size_t)L_ + 8 * hh +
                     (size_t)tb * 32;

  floatx16 acc0, acc1;
#pragma unroll
  for (int r = 0; r < 16; ++r) { acc0[r] = 0.f; acc1[r] = 0.f; }
  const floatx16 zz = acc0;

  // one KV tile against both q-groups; all operands are named registers.
  auto compute = [&](const bf16x8& KF, const bf16x8& VA, const bf16x8& VB) {
    floatx16 s0 = __builtin_amdgcn_mfma_f32_32x32x16_bf16(KF, qf0, zz, 0, 0, 0);
    floatx16 s1 = __builtin_amdgcn_mfma_f32_32x32x16_bf16(KF, qf1, zz, 0, 0, 0);
    bf16x8 pA0, pB0, pA1, pB1;
#pragma unroll
    for (int j = 0; j < 8; ++j) pA0[j] = (__bf16)EXP2(s0[j]);
#pragma unroll
    for (int j = 0; j < 8; ++j) pB0[j] = (__bf16)EXP2(s0[8 + j]);
#pragma unroll
    for (int j = 0; j < 8; ++j) pA1[j] = (__bf16)EXP2(s1[j]);
#pragma unroll
    for (int j = 0; j < 8; ++j) pB1[j] = (__bf16)EXP2(s1[8 + j]);
    acc0 = __builtin_amdgcn_mfma_f32_32x32x16_bf16(VA, pA0, acc0, 0, 0, 0);
    acc0 = __builtin_amdgcn_mfma_f32_32x32x16_bf16(VB, pB0, acc0, 0, 0, 0);
    acc1 = __builtin_amdgcn_mfma_f32_32x32x16_bf16(VA, pA1, acc1, 0, 0, 0);
    acc1 = __builtin_amdgcn_mfma_f32_32x32x16_bf16(VB, pB1, acc1, 0, 0, 0);
  };

  // prologue: tile 0 of this wave's range into stage A
  bf16x8 kA = *(const bf16x8*)(Kp);
  bf16x8 vaA = *(const bf16x8*)(Vq);
  bf16x8 vbA = *(const bf16x8*)(Vq + 16);
  bf16x8 kB, vaB, vbB;

  int t = 0;
#pragma unroll 1
  for (; t + 2 <= ntw; t += 2) {
    // load tile t+1 into B (consumed after compute(A) -> latency hidden)
    kB  = *(const bf16x8*)(Kp + (size_t)(t + 1) * 32 * DH_);
    vaB = *(const bf16x8*)(Vq + (size_t)(t + 1) * 32);
    vbB = *(const bf16x8*)(Vq + (size_t)(t + 1) * 32 + 16);
    compute(kA, vaA, vbA);
    // load tile t+2 into A (guarded: redundant in-bounds reload at range end)
    const size_t t2 = (size_t)((t + 2 < ntw) ? t + 2 : t + 1);
    kA  = *(const bf16x8*)(Kp + t2 * 32 * DH_);
    vaA = *(const bf16x8*)(Vq + t2 * 32);
    vbA = *(const bf16x8*)(Vq + t2 * 32 + 16);
    compute(kB, vaB, vbB);
  }
  if (t < ntw) {  // odd tail: last tile already resident in A
    compute(kA, vaA, vbA);
  }

  // cross-wave K-reduction: half 0 parks both partial accs, half 1 sums.
  if (half == 0) {
#pragma unroll
    for (int r = 0; r < 16; ++r) {
      red[pair][lane][r] = acc0[r];
      red[pair][lane][16 + r] = acc1[r];
    }
  }
  __syncthreads();
  if (half == 0) return;
#pragma unroll
  for (int r = 0; r < 16; ++r) {
    acc0[r] += red[pair][lane][r];
    acc1[r] += red[pair][lane][16 + r];
  }

  // l = row 16 of O^T = acc reg 8 on the hh==0 half; broadcast to hh==1.
  float l0v = acc0[8];
  float l0o = __shfl_xor(l0v, 32, 64);
  float inv0 = __builtin_amdgcn_rcpf(hh ? l0o : l0v);
  float l1v = acc1[8];
  float l1o = __shfl_xor(l1v, 32, 64);
  float inv1 = __builtin_amdgcn_rcpf(hh ? l1o : l1v);

  // regs 0-7 are the 8 valid dh rows for this half: dh = (r&3)+8*(r>>2)+4*hh
  float* obase = out + ((size_t)(b * D_ + h * DH_)) * L_ + q0 + n;
#pragma unroll
  for (int r = 0; r < 8; ++r) {
    const int dh = (r & 3) + 8 * (r >> 2) + 4 * hh;
    obase[(size_t)dh * L_] = acc0[r] * inv0;
    obase[(size_t)dh * L_ + 32] = acc1[r] * inv1;
  }
}

// ---------------------------------------------------------------------------
extern "C" void kernel_launch(void* const* d_in, const int* in_sizes, int n_in,
                              void* d_out, int out_size, void* d_ws,
                              size_t ws_size, hipStream_t stream) {
  const float* queries = (const float*)d_in[0];  // [B, D, L] fp32
  const int*   mask    = (const int*)d_in[1];    // [B, L] int32
  const float* wmem    = (const float*)d_in[2];  // [2D, D] fp32
  const float* wq      = (const float*)d_in[3];  // [D, D] fp32
  float* out = (float*)d_out;                    // [B, D, L] fp32

  // Workspace layout (SEG = 4 MiB):
  //   0: Qs | 1: Ksc (compacted, tau rows) | 2-3: Vpc flat [bh][32][L] |
  //   4: pos [B][L] int (64KB) + cnt [B] int
  const size_t SEG = (size_t)B_ * H_ * L_ * DH_ * sizeof(__bf16);
  __bf16* Qs  = (__bf16*)d_ws;
  __bf16* Ksc = (__bf16*)((char*)d_ws + SEG);
  __bf16* Vpc = (__bf16*)((char*)d_ws + 2 * SEG);
  int* pos = (int*)((char*)d_ws + 4 * SEG);
  int* cnt = pos + B_ * L_;

  // Wb (96 KiB) in d_out scratch: prep writes, proj reads, attn then
  // overwrites ALL of d_out — stream-ordered, race-free.
  __bf16* Wb = (__bf16*)((char*)d_out + (4u << 20));

  prep_kernel<<<32, 256, 0, stream>>>(mask, pos, cnt, Ksc, Vpc, wmem, wq, Wb);
  proj_kernel<<<B_ * (L_ / 32), 512, 0, stream>>>(queries, mask, pos, Wb, Qs,
                                                  Ksc, Vpc);
  attn_kernel<<<B_ * H_ * (L_ / 128), 256, 0, stream>>>(Qs, Ksc, Vpc, cnt, out);
}